// Round 1
// baseline (951.810 us; speedup 1.0000x reference)
//
#include <hip/hip_runtime.h>
#include <cstdint>
#include <cstddef>

constexpr int H_DIM = 1024;
constexpr int NE    = 8;
constexpr int NT    = 16384;
constexpr int NP    = NT * 2;   // total (token, expert) pairs: exactly 2 per token

typedef __attribute__((ext_vector_type(8))) short          short8;
typedef __attribute__((ext_vector_type(8))) unsigned short ushort8;
typedef __attribute__((ext_vector_type(4))) float          f32x4;

__device__ __forceinline__ unsigned short f2bf(float f) {
  union { float f; uint32_t u; } c; c.f = f;
  uint32_t u = c.u;
  u = (u + 0x7fffu + ((u >> 16) & 1u)) >> 16;   // RNE
  return (unsigned short)u;
}
__device__ __forceinline__ float bf2f(unsigned short h) {
  union { uint32_t u; float f; } c; c.u = ((uint32_t)h) << 16;
  return c.f;
}

// ---------------------------------------------------------------------------
// W [E][H][H] (in,out) fp32  ->  T [E][H][H] (out,in) bf16   (LDS-tiled 64x64)
// ---------------------------------------------------------------------------
__global__ __launch_bounds__(256) void transpose_convert_kernel(
    const float* __restrict__ W1, const float* __restrict__ W2,
    unsigned short* __restrict__ T1, unsigned short* __restrict__ T2)
{
  __shared__ float tile[64][65];
  int zi = blockIdx.z;                       // 0..15 : 8 experts x 2 matrices
  const float* W = (zi < 8) ? W1 : W2;
  unsigned short* T = (zi < 8) ? T1 : T2;
  int e  = zi & 7;
  int o0 = blockIdx.x * 64;                  // output-feature tile
  int h0 = blockIdx.y * 64;                  // input-feature tile
  int c  = threadIdx.x & 63;
  int r0 = (threadIdx.x >> 6) * 16;
  const float* src = W + ((size_t)e * H_DIM + h0) * H_DIM + o0;
#pragma unroll
  for (int i = 0; i < 16; ++i)
    tile[r0 + i][c] = src[(size_t)(r0 + i) * H_DIM + c];
  __syncthreads();
  unsigned short* dst = T + ((size_t)e * H_DIM + o0) * H_DIM + h0;
#pragma unroll
  for (int i = 0; i < 16; ++i)
    dst[(size_t)(r0 + i) * H_DIM + c] = f2bf(tile[c][r0 + i]);
}

// ---------------------------------------------------------------------------
// Gating: one wave per token. logits -> softmax -> top2 -> renorm.
// Writes gate_probs (output 1) + tk_e/tk_w + per-expert counts.
// ---------------------------------------------------------------------------
__global__ __launch_bounds__(256) void gate_kernel(
    const float* __restrict__ X, const float* __restrict__ Wg,
    const float* __restrict__ bg, float* __restrict__ gate_out,
    int* __restrict__ tk_e, float* __restrict__ tk_w, int* __restrict__ count)
{
  int wid = threadIdx.x >> 6, lane = threadIdx.x & 63;
  int n = blockIdx.x * 4 + wid;
  const float* xr = X + (size_t)n * H_DIM;

  float acc[8];
#pragma unroll
  for (int e = 0; e < 8; ++e) acc[e] = 0.f;

#pragma unroll 4
  for (int i = 0; i < 16; ++i) {
    int h = lane + 64 * i;
    float xv = xr[h];
    const float4* wg = (const float4*)(Wg + (size_t)h * 8);
    float4 a = wg[0], b = wg[1];
    acc[0] += xv * a.x; acc[1] += xv * a.y; acc[2] += xv * a.z; acc[3] += xv * a.w;
    acc[4] += xv * b.x; acc[5] += xv * b.y; acc[6] += xv * b.z; acc[7] += xv * b.w;
  }
#pragma unroll
  for (int m = 1; m < 64; m <<= 1) {
#pragma unroll
    for (int e = 0; e < 8; ++e) acc[e] += __shfl_xor(acc[e], m);
  }
#pragma unroll
  for (int e = 0; e < 8; ++e) acc[e] += bg[e];

  // softmax over 8 (all lanes redundantly)
  float mx = acc[0];
#pragma unroll
  for (int e = 1; e < 8; ++e) mx = fmaxf(mx, acc[e]);
  float g[8], s = 0.f;
#pragma unroll
  for (int e = 0; e < 8; ++e) { g[e] = __expf(acc[e] - mx); s += g[e]; }
  float inv = 1.f / s;
#pragma unroll
  for (int e = 0; e < 8; ++e) g[e] *= inv;

  // top-2 (first index wins ties, matching lax.top_k)
  int e0 = 0; float b0 = g[0];
#pragma unroll
  for (int e = 1; e < 8; ++e) if (g[e] > b0) { b0 = g[e]; e0 = e; }
  int e1 = -1; float b1v = -1.f;
#pragma unroll
  for (int e = 0; e < 8; ++e) if (e != e0 && g[e] > b1v) { b1v = g[e]; e1 = e; }
  float s2 = b0 + b1v + 1e-9f;

  if (lane == 0) {
    float4 p0 = make_float4(g[0], g[1], g[2], g[3]);
    float4 p1 = make_float4(g[4], g[5], g[6], g[7]);
    float4* gp = (float4*)(gate_out + (size_t)n * 8);
    gp[0] = p0; gp[1] = p1;
    tk_e[2 * n] = e0; tk_e[2 * n + 1] = e1;
    tk_w[2 * n] = b0 / s2; tk_w[2 * n + 1] = b1v / s2;
    atomicAdd(&count[e0], 1);
    atomicAdd(&count[e1], 1);
  }
}

__global__ void scan_kernel(const int* __restrict__ count,
                            int* __restrict__ offs, int* __restrict__ cursor)
{
  if (threadIdx.x == 0) {
    int o = 0;
    for (int e = 0; e < 8; ++e) { offs[e] = o; cursor[e] = o; o += count[e]; }
  }
}

__global__ __launch_bounds__(256) void place_kernel(
    const int* __restrict__ tk_e, int* __restrict__ cursor,
    int* __restrict__ pairTok, int* __restrict__ pairExp, int* __restrict__ slots)
{
  int n = blockIdx.x * 256 + threadIdx.x;
#pragma unroll
  for (int k = 0; k < 2; ++k) {
    int e = tk_e[2 * n + k];
    int s = atomicAdd(&cursor[e], 1);
    pairTok[s] = n; pairExp[s] = e; slots[2 * n + k] = s;
  }
}

// ---------------------------------------------------------------------------
// MFMA GEMM: C[m, col] = A[m, :] @ Bt[e][col, :] + bias[e][col]  (bf16 in, bf16 out)
// Tile 128x128x32, 4 waves, 16x16x32 bf16 frags. A gathered (GEMM1) or direct.
// ---------------------------------------------------------------------------
template<bool GATHER>
__global__ __launch_bounds__(256) void gemm_kernel(
    const float* __restrict__ Xf,            // GATHER: fp32 activations [NT][H]
    const unsigned short* __restrict__ Ab,   // !GATHER: bf16 rows [NP][H]
    const unsigned short* __restrict__ Bt,   // [E][H(out)][H(in)] bf16
    const float* __restrict__ bias,          // [E][H]
    const int* __restrict__ pairTok,
    const int* __restrict__ count, const int* __restrict__ offs,
    unsigned short* __restrict__ Out)        // [NP][H] bf16
{
  __shared__ unsigned short As[128 * 40];
  __shared__ unsigned short Bs[128 * 40];

  int e  = blockIdx.z;
  int mt = blockIdx.y;
  int nt = blockIdx.x;
  int cnt = count[e];
  if (mt * 128 >= cnt) return;
  int base = offs[e];
  int tid = threadIdx.x;

  // staging: 2 threads per row, 16 elements (32B) each
  int srow = tid >> 1, seg = tid & 1;
  int m = mt * 128 + srow; if (m > cnt - 1) m = cnt - 1;
  const float* aSrcF = nullptr; const unsigned short* aSrcB = nullptr;
  if (GATHER) { int tok = pairTok[base + m]; aSrcF = Xf + (size_t)tok * H_DIM + seg * 16; }
  else        { aSrcB = Ab + (size_t)(base + m) * H_DIM + seg * 16; }
  const unsigned short* bSrc = Bt + ((size_t)e * H_DIM + nt * 128 + srow) * H_DIM + seg * 16;
  unsigned short* aDst = &As[srow * 40 + seg * 16];
  unsigned short* bDst = &Bs[srow * 40 + seg * 16];

  int wid = tid >> 6, lane = tid & 63;
  int wr = wid >> 1, wc = wid & 1;
  int lr = lane & 15, lg = lane >> 4;

  f32x4 acc[4][4] = {};

  for (int k0 = 0; k0 < H_DIM; k0 += 32) {
    __syncthreads();
    if (GATHER) {
      const float4* p = (const float4*)(aSrcF + k0);
      float4 f0 = p[0], f1 = p[1], f2 = p[2], f3 = p[3];
      ushort8 u0, u1;
      u0[0]=f2bf(f0.x); u0[1]=f2bf(f0.y); u0[2]=f2bf(f0.z); u0[3]=f2bf(f0.w);
      u0[4]=f2bf(f1.x); u0[5]=f2bf(f1.y); u0[6]=f2bf(f1.z); u0[7]=f2bf(f1.w);
      u1[0]=f2bf(f2.x); u1[1]=f2bf(f2.y); u1[2]=f2bf(f2.z); u1[3]=f2bf(f2.w);
      u1[4]=f2bf(f3.x); u1[5]=f2bf(f3.y); u1[6]=f2bf(f3.z); u1[7]=f2bf(f3.w);
      *(ushort8*)aDst = u0; *(ushort8*)(aDst + 8) = u1;
    } else {
      const ushort8* p = (const ushort8*)(aSrcB + k0);
      *(ushort8*)aDst = p[0]; *(ushort8*)(aDst + 8) = p[1];
    }
    {
      const ushort8* p = (const ushort8*)(bSrc + k0);
      *(ushort8*)bDst = p[0]; *(ushort8*)(bDst + 8) = p[1];
    }
    __syncthreads();

    short8 af[4], bfr[4];
#pragma unroll
    for (int i = 0; i < 4; ++i) {
      af[i]  = *(const short8*)&As[(wr * 64 + i * 16 + lr) * 40 + lg * 8];
      bfr[i] = *(const short8*)&Bs[(wc * 64 + i * 16 + lr) * 40 + lg * 8];
    }
#pragma unroll
    for (int m4 = 0; m4 < 4; ++m4)
#pragma unroll
      for (int n4 = 0; n4 < 4; ++n4)
        acc[m4][n4] = __builtin_amdgcn_mfma_f32_16x16x32_bf16(af[m4], bfr[n4], acc[m4][n4], 0, 0, 0);
  }

  // epilogue: + bias, write bf16
#pragma unroll
  for (int n4 = 0; n4 < 4; ++n4) {
    int col = nt * 128 + wc * 64 + n4 * 16 + lr;
    float bv = bias[e * H_DIM + col];
#pragma unroll
    for (int m4 = 0; m4 < 4; ++m4) {
#pragma unroll
      for (int r = 0; r < 4; ++r) {
        int grow = mt * 128 + wr * 64 + m4 * 16 + 4 * lg + r;
        if (grow < cnt)
          Out[(size_t)(base + grow) * H_DIM + col] = f2bf(acc[m4][n4][r] + bv);
      }
    }
  }
}

// ---------------------------------------------------------------------------
// In-place relu(LayerNorm(row)) on bf16 rows; one wave per row.
// ---------------------------------------------------------------------------
__global__ __launch_bounds__(256) void ln_relu_kernel(
    unsigned short* __restrict__ buf, const float* __restrict__ gamma,
    const float* __restrict__ beta, const int* __restrict__ pairExp)
{
  int wid = threadIdx.x >> 6, lane = threadIdx.x & 63;
  int row = blockIdx.x * 4 + wid;
  int e = pairExp[row];
  unsigned short* r = buf + (size_t)row * H_DIM;
  ushort8 u0 = ((const ushort8*)r)[lane];
  ushort8 u1 = ((const ushort8*)r)[lane + 64];
  float v[16];
#pragma unroll
  for (int j = 0; j < 8; ++j) { v[j] = bf2f(u0[j]); v[8 + j] = bf2f(u1[j]); }
  float s = 0.f, ss = 0.f;
#pragma unroll
  for (int j = 0; j < 16; ++j) { s += v[j]; ss += v[j] * v[j]; }
#pragma unroll
  for (int m = 1; m < 64; m <<= 1) { s += __shfl_xor(s, m); ss += __shfl_xor(ss, m); }
  float mean = s * (1.f / 1024.f);
  float var  = ss * (1.f / 1024.f) - mean * mean;
  float rs   = rsqrtf(var + 1e-5f);

  int h0 = lane * 8, h1 = 512 + lane * 8;
  const float4* gp0 = (const float4*)(gamma + (size_t)e * H_DIM + h0);
  const float4* bp0 = (const float4*)(beta  + (size_t)e * H_DIM + h0);
  const float4* gp1 = (const float4*)(gamma + (size_t)e * H_DIM + h1);
  const float4* bp1 = (const float4*)(beta  + (size_t)e * H_DIM + h1);
  float4 ga = gp0[0], gb = gp0[1], gc = gp1[0], gd = gp1[1];
  float4 ba = bp0[0], bb = bp0[1], bc = bp1[0], bd = bp1[1];
  float gv[16] = {ga.x,ga.y,ga.z,ga.w, gb.x,gb.y,gb.z,gb.w,
                  gc.x,gc.y,gc.z,gc.w, gd.x,gd.y,gd.z,gd.w};
  float bv[16] = {ba.x,ba.y,ba.z,ba.w, bb.x,bb.y,bb.z,bb.w,
                  bc.x,bc.y,bc.z,bc.w, bd.x,bd.y,bd.z,bd.w};
#pragma unroll
  for (int j = 0; j < 8; ++j) {
    float t0 = fmaxf((v[j]     - mean) * rs * gv[j]     + bv[j],     0.f);
    float t1 = fmaxf((v[8 + j] - mean) * rs * gv[8 + j] + bv[8 + j], 0.f);
    u0[j] = f2bf(t0); u1[j] = f2bf(t1);
  }
  ((ushort8*)r)[lane] = u0; ((ushort8*)r)[lane + 64] = u1;
}

// ---------------------------------------------------------------------------
// Combine: per token, LN2 each of its 2 expert rows, y=relu(x+u), out = sum w*y
// ---------------------------------------------------------------------------
__global__ __launch_bounds__(256) void combine_kernel(
    const unsigned short* __restrict__ buf2, const float* __restrict__ X,
    const float* __restrict__ g2, const float* __restrict__ be2,
    const int* __restrict__ slots, const int* __restrict__ tk_e,
    const float* __restrict__ tk_w, float* __restrict__ out)
{
  int wid = threadIdx.x >> 6, lane = threadIdx.x & 63;
  int n = blockIdx.x * 4 + wid;
  int h0 = lane * 8, h1 = 512 + lane * 8;

  const float4* xp0 = (const float4*)(X + (size_t)n * H_DIM + h0);
  const float4* xp1 = (const float4*)(X + (size_t)n * H_DIM + h1);
  float4 xa = xp0[0], xb = xp0[1], xc = xp1[0], xd = xp1[1];
  float xv[16] = {xa.x,xa.y,xa.z,xa.w, xb.x,xb.y,xb.z,xb.w,
                  xc.x,xc.y,xc.z,xc.w, xd.x,xd.y,xd.z,xd.w};
  float o[16];
#pragma unroll
  for (int j = 0; j < 16; ++j) o[j] = 0.f;

#pragma unroll
  for (int k = 0; k < 2; ++k) {
    int slot = slots[2 * n + k];
    int e = tk_e[2 * n + k];
    float w = tk_w[2 * n + k];
    const unsigned short* r = buf2 + (size_t)slot * H_DIM;
    ushort8 u0 = ((const ushort8*)r)[lane];
    ushort8 u1 = ((const ushort8*)r)[lane + 64];
    float v[16];
#pragma unroll
    for (int j = 0; j < 8; ++j) { v[j] = bf2f(u0[j]); v[8 + j] = bf2f(u1[j]); }
    float s = 0.f, ss = 0.f;
#pragma unroll
    for (int j = 0; j < 16; ++j) { s += v[j]; ss += v[j] * v[j]; }
#pragma unroll
    for (int m = 1; m < 64; m <<= 1) { s += __shfl_xor(s, m); ss += __shfl_xor(ss, m); }
    float mean = s * (1.f / 1024.f);
    float var  = ss * (1.f / 1024.f) - mean * mean;
    float rs   = rsqrtf(var + 1e-5f);

    const float4* gp0 = (const float4*)(g2  + (size_t)e * H_DIM + h0);
    const float4* bp0 = (const float4*)(be2 + (size_t)e * H_DIM + h0);
    const float4* gp1 = (const float4*)(g2  + (size_t)e * H_DIM + h1);
    const float4* bp1 = (const float4*)(be2 + (size_t)e * H_DIM + h1);
    float4 ga = gp0[0], gb = gp0[1], gc = gp1[0], gd = gp1[1];
    float4 ba = bp0[0], bb = bp0[1], bc = bp1[0], bd = bp1[1];
    float gv[16] = {ga.x,ga.y,ga.z,ga.w, gb.x,gb.y,gb.z,gb.w,
                    gc.x,gc.y,gc.z,gc.w, gd.x,gd.y,gd.z,gd.w};
    float bvv[16] = {ba.x,ba.y,ba.z,ba.w, bb.x,bb.y,bb.z,bb.w,
                     bc.x,bc.y,bc.z,bc.w, bd.x,bd.y,bd.z,bd.w};
#pragma unroll
    for (int j = 0; j < 16; ++j) {
      float u = (v[j] - mean) * rs * gv[j] + bvv[j];
      float y = fmaxf(xv[j] + u, 0.f);
      o[j] += w * y;
    }
  }

  float4* op0 = (float4*)(out + (size_t)n * H_DIM + h0);
  float4* op1 = (float4*)(out + (size_t)n * H_DIM + h1);
  op0[0] = make_float4(o[0], o[1], o[2], o[3]);
  op0[1] = make_float4(o[4], o[5], o[6], o[7]);
  op1[0] = make_float4(o[8], o[9], o[10], o[11]);
  op1[1] = make_float4(o[12], o[13], o[14], o[15]);
}

// ---------------------------------------------------------------------------
extern "C" void kernel_launch(void* const* d_in, const int* in_sizes, int n_in,
                              void* d_out, int out_size, void* d_ws, size_t ws_size,
                              hipStream_t stream)
{
  const float* x   = (const float*)d_in[0];
  const float* Wg  = (const float*)d_in[1];
  const float* bg  = (const float*)d_in[2];
  const float* W1  = (const float*)d_in[3];
  const float* b1  = (const float*)d_in[4];
  const float* g1  = (const float*)d_in[5];
  const float* be1 = (const float*)d_in[6];
  const float* W2  = (const float*)d_in[7];
  const float* b2  = (const float*)d_in[8];
  const float* g2  = (const float*)d_in[9];
  const float* be2 = (const float*)d_in[10];
  float* out = (float*)d_out;
  float* gate_out = out + (size_t)NT * H_DIM;

  char* ws = (char*)d_ws;
  size_t off = 0;
  auto alloc = [&](size_t bytes) { char* p = ws + off; off += (bytes + 255) & ~(size_t)255; return p; };
  unsigned short* w1bt = (unsigned short*)alloc((size_t)NE * H_DIM * H_DIM * 2);
  unsigned short* w2bt = (unsigned short*)alloc((size_t)NE * H_DIM * H_DIM * 2);
  unsigned short* buf1 = (unsigned short*)alloc((size_t)NP * H_DIM * 2);
  unsigned short* buf2 = (unsigned short*)alloc((size_t)NP * H_DIM * 2);
  int*   tk_e    = (int*)alloc((size_t)NP * 4);
  float* tk_w    = (float*)alloc((size_t)NP * 4);
  int*   pairTok = (int*)alloc((size_t)NP * 4);
  int*   pairExp = (int*)alloc((size_t)NP * 4);
  int*   slots   = (int*)alloc((size_t)NP * 4);
  int*   count   = (int*)alloc(8 * 4);
  int*   offs    = (int*)alloc(8 * 4);
  int*   cursor  = (int*)alloc(8 * 4);
  (void)in_sizes; (void)n_in; (void)out_size; (void)ws_size;

  hipMemsetAsync(count, 0, 8 * 4, stream);

  transpose_convert_kernel<<<dim3(16, 16, 16), 256, 0, stream>>>(W1, W2, w1bt, w2bt);
  gate_kernel<<<dim3(NT / 4), 256, 0, stream>>>(x, Wg, bg, gate_out, tk_e, tk_w, count);
  scan_kernel<<<dim3(1), 64, 0, stream>>>(count, offs, cursor);
  place_kernel<<<dim3(NT / 256), 256, 0, stream>>>(tk_e, cursor, pairTok, pairExp, slots);
  gemm_kernel<true><<<dim3(8, 128, 8), 256, 0, stream>>>(
      x, nullptr, w1bt, b1, pairTok, count, offs, buf1);
  ln_relu_kernel<<<dim3(NP / 4), 256, 0, stream>>>(buf1, g1, be1, pairExp);
  gemm_kernel<false><<<dim3(8, 128, 8), 256, 0, stream>>>(
      nullptr, buf1, w2bt, b2, pairTok, count, offs, buf2);
  combine_kernel<<<dim3(NT / 4), 256, 0, stream>>>(
      buf2, x, g2, be2, slots, tk_e, tk_w, out);
}

// Round 2
// 423.896 us; speedup vs baseline: 2.2454x; 2.2454x over previous
//
#include <hip/hip_runtime.h>
#include <cstdint>
#include <cstddef>

constexpr int H_DIM = 1024;
constexpr int NE    = 8;
constexpr int NT    = 16384;
constexpr int NP    = NT * 2;   // total (token, expert) pairs: exactly 2 per token

typedef __attribute__((ext_vector_type(8))) short          short8;
typedef __attribute__((ext_vector_type(8))) unsigned short ushort8;
typedef __attribute__((ext_vector_type(4))) unsigned short ushort4v;
typedef __attribute__((ext_vector_type(4))) float          f32x4;

__device__ __forceinline__ unsigned short f2bf(float f) {
  union { float f; uint32_t u; } c; c.f = f;
  uint32_t u = c.u;
  u = (u + 0x7fffu + ((u >> 16) & 1u)) >> 16;   // RNE
  return (unsigned short)u;
}
__device__ __forceinline__ float bf2f(unsigned short h) {
  union { uint32_t u; float f; } c; c.u = ((uint32_t)h) << 16;
  return c.f;
}

// async 16B global -> LDS (wave-uniform LDS base + lane*16; global addr per-lane)
__device__ __forceinline__ void gload16(const unsigned short* g, unsigned short* l) {
  __builtin_amdgcn_global_load_lds((const __attribute__((address_space(1))) void*)g,
                                   (__attribute__((address_space(3))) void*)l, 16, 0, 0);
}

// ---------------------------------------------------------------------------
// W [E][H][H] (in,out) fp32  ->  T [E][H][H] (out,in) bf16   (LDS-tiled 64x64)
// ---------------------------------------------------------------------------
__global__ __launch_bounds__(256) void transpose_convert_kernel(
    const float* __restrict__ W1, const float* __restrict__ W2,
    unsigned short* __restrict__ T1, unsigned short* __restrict__ T2)
{
  __shared__ float tile[64][65];
  int zi = blockIdx.z;                       // 0..15 : 8 experts x 2 matrices
  const float* W = (zi < 8) ? W1 : W2;
  unsigned short* T = (zi < 8) ? T1 : T2;
  int e  = zi & 7;
  int o0 = blockIdx.x * 64;                  // output-feature tile
  int h0 = blockIdx.y * 64;                  // input-feature tile
  int c  = threadIdx.x & 63;
  int r0 = (threadIdx.x >> 6) * 16;
  const float* src = W + ((size_t)e * H_DIM + h0) * H_DIM + o0;
#pragma unroll
  for (int i = 0; i < 16; ++i)
    tile[r0 + i][c] = src[(size_t)(r0 + i) * H_DIM + c];
  __syncthreads();
  unsigned short* dst = T + ((size_t)e * H_DIM + o0) * H_DIM + h0;
#pragma unroll
  for (int i = 0; i < 16; ++i)
    dst[(size_t)(r0 + i) * H_DIM + c] = f2bf(tile[c][r0 + i]);
}

// ---------------------------------------------------------------------------
// Fused: X fp32 -> Xb bf16  +  gating (softmax over 8, top-2, renorm).
// One wave per token. NO global atomics.
// ---------------------------------------------------------------------------
__global__ __launch_bounds__(256) void xgate_kernel(
    const float* __restrict__ X, const float* __restrict__ Wg,
    const float* __restrict__ bg, unsigned short* __restrict__ Xb,
    float* __restrict__ gate_out, int* __restrict__ tk_e, float* __restrict__ tk_w)
{
  int wid = threadIdx.x >> 6, lane = threadIdx.x & 63;
  int n = blockIdx.x * 4 + wid;
  const float* xr = X + (size_t)n * H_DIM;

  // lane owns elements h = lane*16 .. lane*16+15
  const float4* xp = (const float4*)(xr + lane * 16);
  float4 f0 = xp[0], f1 = xp[1], f2 = xp[2], f3 = xp[3];
  float v[16] = {f0.x,f0.y,f0.z,f0.w, f1.x,f1.y,f1.z,f1.w,
                 f2.x,f2.y,f2.z,f2.w, f3.x,f3.y,f3.z,f3.w};

  // bf16 copy of the row
  ushort8 u0, u1;
#pragma unroll
  for (int j = 0; j < 8; ++j) { u0[j] = f2bf(v[j]); u1[j] = f2bf(v[8 + j]); }
  ushort8* xb = (ushort8*)(Xb + (size_t)n * H_DIM + lane * 16);
  xb[0] = u0; xb[1] = u1;

  // gate logits
  float acc[8];
#pragma unroll
  for (int e = 0; e < 8; ++e) acc[e] = 0.f;
#pragma unroll
  for (int j = 0; j < 16; ++j) {
    int h = lane * 16 + j;
    const float4* wg = (const float4*)(Wg + (size_t)h * 8);
    float4 a = wg[0], b = wg[1];
    float xv = v[j];
    acc[0] += xv * a.x; acc[1] += xv * a.y; acc[2] += xv * a.z; acc[3] += xv * a.w;
    acc[4] += xv * b.x; acc[5] += xv * b.y; acc[6] += xv * b.z; acc[7] += xv * b.w;
  }
#pragma unroll
  for (int m = 1; m < 64; m <<= 1) {
#pragma unroll
    for (int e = 0; e < 8; ++e) acc[e] += __shfl_xor(acc[e], m);
  }
#pragma unroll
  for (int e = 0; e < 8; ++e) acc[e] += bg[e];

  // softmax over 8 (all lanes redundantly)
  float mx = acc[0];
#pragma unroll
  for (int e = 1; e < 8; ++e) mx = fmaxf(mx, acc[e]);
  float g[8], s = 0.f;
#pragma unroll
  for (int e = 0; e < 8; ++e) { g[e] = __expf(acc[e] - mx); s += g[e]; }
  float inv = 1.f / s;
#pragma unroll
  for (int e = 0; e < 8; ++e) g[e] *= inv;

  // top-2 (first index wins ties, matching lax.top_k)
  int e0 = 0; float b0 = g[0];
#pragma unroll
  for (int e = 1; e < 8; ++e) if (g[e] > b0) { b0 = g[e]; e0 = e; }
  int e1 = -1; float b1v = -1.f;
#pragma unroll
  for (int e = 0; e < 8; ++e) if (e != e0 && g[e] > b1v) { b1v = g[e]; e1 = e; }
  float s2 = b0 + b1v + 1e-9f;

  if (lane == 0) {
    float4* gp = (float4*)(gate_out + (size_t)n * 8);
    gp[0] = make_float4(g[0], g[1], g[2], g[3]);
    gp[1] = make_float4(g[4], g[5], g[6], g[7]);
    tk_e[2 * n] = e0; tk_e[2 * n + 1] = e1;
    tk_w[2 * n] = b0 / s2; tk_w[2 * n + 1] = b1v / s2;
  }
}

// ---------------------------------------------------------------------------
// Routing without contended atomics: block-hist -> scan -> block-place.
// 64 blocks x 512 entries each.
// ---------------------------------------------------------------------------
__global__ __launch_bounds__(256) void hist_kernel(
    const int* __restrict__ tk_e, int* __restrict__ blockHist)
{
  __shared__ int h[8];
  if (threadIdx.x < 8) h[threadIdx.x] = 0;
  __syncthreads();
  int i0 = blockIdx.x * 512 + threadIdx.x;
  atomicAdd(&h[tk_e[i0]], 1);
  atomicAdd(&h[tk_e[i0 + 256]], 1);
  __syncthreads();
  if (threadIdx.x < 8) blockHist[blockIdx.x * 8 + threadIdx.x] = h[threadIdx.x];
}

__global__ void scan_kernel(const int* __restrict__ blockHist,
                            int* __restrict__ blockBase,
                            int* __restrict__ count, int* __restrict__ offs)
{
  int e = threadIdx.x;
  if (e < 8) {
    int run = 0;
    for (int b = 0; b < 64; ++b) { blockBase[b * 8 + e] = run; run += blockHist[b * 8 + e]; }
    count[e] = run;
  }
  __syncthreads();
  if (threadIdx.x == 0) {
    int o = 0;
    for (int k = 0; k < 8; ++k) { offs[k] = o; o += count[k]; }
  }
  __syncthreads();
  if (e < 8) {
    int o = offs[e];
    for (int b = 0; b < 64; ++b) blockBase[b * 8 + e] += o;
  }
}

__global__ __launch_bounds__(256) void place_kernel(
    const int* __restrict__ tk_e, const int* __restrict__ blockBase,
    int* __restrict__ pairTok, int* __restrict__ pairExp, int* __restrict__ slots)
{
  __shared__ int cur[8];
  if (threadIdx.x < 8) cur[threadIdx.x] = blockBase[blockIdx.x * 8 + threadIdx.x];
  __syncthreads();
#pragma unroll
  for (int j = 0; j < 2; ++j) {
    int i = blockIdx.x * 512 + j * 256 + threadIdx.x;
    int e = tk_e[i];
    int s = atomicAdd(&cur[e], 1);
    pairTok[s] = i >> 1; pairExp[s] = e; slots[i] = s;
  }
}

// ---------------------------------------------------------------------------
// MFMA GEMM (m97 structure): tile 128x128x32, 4 waves, global_load_lds x16,
// linear LDS. C[m,col] = A[m,:] @ Bt[e][col,:] + bias[e][col]; bf16 in/out.
// ---------------------------------------------------------------------------
template<bool GATHER>
__global__ __launch_bounds__(256) void gemm_kernel(
    const unsigned short* __restrict__ Ab,   // GATHER: Xb [NT][H]; else buf rows [NP][H]
    const unsigned short* __restrict__ Bt,   // [E][H(out)][H(in)] bf16
    const float* __restrict__ bias,          // [E][H]
    const int* __restrict__ pairTok,
    const int* __restrict__ count, const int* __restrict__ offs,
    unsigned short* __restrict__ Out)        // [NP][H] bf16
{
  __shared__ unsigned short As[128 * 32];    // 8 KB, linear [row][k], 64B rows
  __shared__ unsigned short Bs[128 * 32];

  const int e  = blockIdx.z;
  const int mt = blockIdx.y;
  const int nt = blockIdx.x;
  const int cnt = count[e];
  if (mt * 128 >= cnt) return;
  const int base = offs[e];
  const int tid = threadIdx.x;
  const int w = tid >> 6, l = tid & 63;

  // staging geometry: issue j (0/1) of wave w covers LDS bytes j*4096 + w*1024 + l*16
  // -> row = j*64 + w*16 + (l>>2), element offset within row = (l&3)*8
  const int r0 = w * 16 + (l >> 2);
  const int kk = (l & 3) * 8;

  int m0 = mt * 128 + r0;      if (m0 >= cnt) m0 = cnt - 1;
  int m1 = mt * 128 + r0 + 64; if (m1 >= cnt) m1 = cnt - 1;
  size_t arow0, arow1;
  if (GATHER) { arow0 = (size_t)pairTok[base + m0]; arow1 = (size_t)pairTok[base + m1]; }
  else        { arow0 = (size_t)(base + m0);        arow1 = (size_t)(base + m1); }
  const unsigned short* aS0 = Ab + arow0 * H_DIM + kk;
  const unsigned short* aS1 = Ab + arow1 * H_DIM + kk;
  const unsigned short* bS0 = Bt + ((size_t)e * H_DIM + nt * 128 + r0) * H_DIM + kk;
  const unsigned short* bS1 = bS0 + (size_t)64 * H_DIM;
  unsigned short* aD0 = As + w * 512;
  unsigned short* aD1 = As + 2048 + w * 512;
  unsigned short* bD0 = Bs + w * 512;
  unsigned short* bD1 = Bs + 2048 + w * 512;

  const int wr = w >> 1, wc = w & 1;
  const int lr = l & 15, lg = l >> 4;

  f32x4 acc[4][4] = {};

  for (int k0 = 0; k0 < H_DIM; k0 += 32) {
    __syncthreads();
    gload16(aS0 + k0, aD0);
    gload16(aS1 + k0, aD1);
    gload16(bS0 + k0, bD0);
    gload16(bS1 + k0, bD1);
    __syncthreads();

    short8 af[4], bfr[4];
#pragma unroll
    for (int i = 0; i < 4; ++i) {
      af[i]  = *(const short8*)&As[(wr * 64 + i * 16 + lr) * 32 + lg * 8];
      bfr[i] = *(const short8*)&Bs[(wc * 64 + i * 16 + lr) * 32 + lg * 8];
    }
#pragma unroll
    for (int m4 = 0; m4 < 4; ++m4)
#pragma unroll
      for (int n4 = 0; n4 < 4; ++n4)
        acc[m4][n4] = __builtin_amdgcn_mfma_f32_16x16x32_bf16(af[m4], bfr[n4], acc[m4][n4], 0, 0, 0);
  }

  // epilogue: + bias, write bf16
#pragma unroll
  for (int n4 = 0; n4 < 4; ++n4) {
    int col = nt * 128 + wc * 64 + n4 * 16 + lr;
    float bv = bias[e * H_DIM + col];
#pragma unroll
    for (int m4 = 0; m4 < 4; ++m4) {
#pragma unroll
      for (int r = 0; r < 4; ++r) {
        int grow = mt * 128 + wr * 64 + m4 * 16 + 4 * lg + r;
        if (grow < cnt)
          Out[(size_t)(base + grow) * H_DIM + col] = f2bf(acc[m4][n4][r] + bv);
      }
    }
  }
}

// ---------------------------------------------------------------------------
// In-place relu(LayerNorm(row)) on bf16 rows; one wave per row.
// ---------------------------------------------------------------------------
__global__ __launch_bounds__(256) void ln_relu_kernel(
    unsigned short* __restrict__ buf, const float* __restrict__ gamma,
    const float* __restrict__ beta, const int* __restrict__ pairExp)
{
  int wid = threadIdx.x >> 6, lane = threadIdx.x & 63;
  int row = blockIdx.x * 4 + wid;
  int e = pairExp[row];
  unsigned short* r = buf + (size_t)row * H_DIM;
  ushort8 u0 = ((const ushort8*)r)[lane];
  ushort8 u1 = ((const ushort8*)r)[lane + 64];
  float v[16];
#pragma unroll
  for (int j = 0; j < 8; ++j) { v[j] = bf2f(u0[j]); v[8 + j] = bf2f(u1[j]); }
  float s = 0.f, ss = 0.f;
#pragma unroll
  for (int j = 0; j < 16; ++j) { s += v[j]; ss += v[j] * v[j]; }
#pragma unroll
  for (int m = 1; m < 64; m <<= 1) { s += __shfl_xor(s, m); ss += __shfl_xor(ss, m); }
  float mean = s * (1.f / 1024.f);
  float var  = ss * (1.f / 1024.f) - mean * mean;
  float rs   = rsqrtf(var + 1e-5f);

  int h0 = lane * 8, h1 = 512 + lane * 8;
  const float4* gp0 = (const float4*)(gamma + (size_t)e * H_DIM + h0);
  const float4* bp0 = (const float4*)(beta  + (size_t)e * H_DIM + h0);
  const float4* gp1 = (const float4*)(gamma + (size_t)e * H_DIM + h1);
  const float4* bp1 = (const float4*)(beta  + (size_t)e * H_DIM + h1);
  float4 ga = gp0[0], gb = gp0[1], gc = gp1[0], gd = gp1[1];
  float4 ba = bp0[0], bb = bp0[1], bc = bp1[0], bd = bp1[1];
  float gv[16] = {ga.x,ga.y,ga.z,ga.w, gb.x,gb.y,gb.z,gb.w,
                  gc.x,gc.y,gc.z,gc.w, gd.x,gd.y,gd.z,gd.w};
  float bv[16] = {ba.x,ba.y,ba.z,ba.w, bb.x,bb.y,bb.z,bb.w,
                  bc.x,bc.y,bc.z,bc.w, bd.x,bd.y,bd.z,bd.w};
#pragma unroll
  for (int j = 0; j < 8; ++j) {
    float t0 = fmaxf((v[j]     - mean) * rs * gv[j]     + bv[j],     0.f);
    float t1 = fmaxf((v[8 + j] - mean) * rs * gv[8 + j] + bv[8 + j], 0.f);
    u0[j] = f2bf(t0); u1[j] = f2bf(t1);
  }
  ((ushort8*)r)[lane] = u0; ((ushort8*)r)[lane + 64] = u1;
}

// ---------------------------------------------------------------------------
// Combine: per token, LN2 each of its 2 expert rows, y=relu(x+u), out = sum w*y
// ---------------------------------------------------------------------------
__global__ __launch_bounds__(256) void combine_kernel(
    const unsigned short* __restrict__ buf2, const float* __restrict__ X,
    const float* __restrict__ g2, const float* __restrict__ be2,
    const int* __restrict__ slots, const int* __restrict__ tk_e,
    const float* __restrict__ tk_w, float* __restrict__ out)
{
  int wid = threadIdx.x >> 6, lane = threadIdx.x & 63;
  int n = blockIdx.x * 4 + wid;
  int h0 = lane * 8, h1 = 512 + lane * 8;

  const float4* xp0 = (const float4*)(X + (size_t)n * H_DIM + h0);
  const float4* xp1 = (const float4*)(X + (size_t)n * H_DIM + h1);
  float4 xa = xp0[0], xb = xp0[1], xc = xp1[0], xd = xp1[1];
  float xv[16] = {xa.x,xa.y,xa.z,xa.w, xb.x,xb.y,xb.z,xb.w,
                  xc.x,xc.y,xc.z,xc.w, xd.x,xd.y,xd.z,xd.w};
  float o[16];
#pragma unroll
  for (int j = 0; j < 16; ++j) o[j] = 0.f;

#pragma unroll
  for (int k = 0; k < 2; ++k) {
    int slot = slots[2 * n + k];
    int e = tk_e[2 * n + k];
    float w = tk_w[2 * n + k];
    const unsigned short* r = buf2 + (size_t)slot * H_DIM;
    ushort8 u0 = ((const ushort8*)r)[lane];
    ushort8 u1 = ((const ushort8*)r)[lane + 64];
    float v[16];
#pragma unroll
    for (int j = 0; j < 8; ++j) { v[j] = bf2f(u0[j]); v[8 + j] = bf2f(u1[j]); }
    float s = 0.f, ss = 0.f;
#pragma unroll
    for (int j = 0; j < 16; ++j) { s += v[j]; ss += v[j] * v[j]; }
#pragma unroll
    for (int m = 1; m < 64; m <<= 1) { s += __shfl_xor(s, m); ss += __shfl_xor(ss, m); }
    float mean = s * (1.f / 1024.f);
    float var  = ss * (1.f / 1024.f) - mean * mean;
    float rs   = rsqrtf(var + 1e-5f);

    const float4* gp0 = (const float4*)(g2  + (size_t)e * H_DIM + h0);
    const float4* bp0 = (const float4*)(be2 + (size_t)e * H_DIM + h0);
    const float4* gp1 = (const float4*)(g2  + (size_t)e * H_DIM + h1);
    const float4* bp1 = (const float4*)(be2 + (size_t)e * H_DIM + h1);
    float4 ga = gp0[0], gb = gp0[1], gc = gp1[0], gd = gp1[1];
    float4 ba = bp0[0], bb = bp0[1], bc = bp1[0], bd = bp1[1];
    float gv[16] = {ga.x,ga.y,ga.z,ga.w, gb.x,gb.y,gb.z,gb.w,
                    gc.x,gc.y,gc.z,gc.w, gd.x,gd.y,gd.z,gd.w};
    float bvv[16] = {ba.x,ba.y,ba.z,ba.w, bb.x,bb.y,bb.z,bb.w,
                     bc.x,bc.y,bc.z,bc.w, bd.x,bd.y,bd.z,bd.w};
#pragma unroll
    for (int j = 0; j < 16; ++j) {
      float u = (v[j] - mean) * rs * gv[j] + bvv[j];
      float y = fmaxf(xv[j] + u, 0.f);
      o[j] += w * y;
    }
  }

  float4* op0 = (float4*)(out + (size_t)n * H_DIM + h0);
  float4* op1 = (float4*)(out + (size_t)n * H_DIM + h1);
  op0[0] = make_float4(o[0], o[1], o[2], o[3]);
  op0[1] = make_float4(o[4], o[5], o[6], o[7]);
  op1[0] = make_float4(o[8], o[9], o[10], o[11]);
  op1[1] = make_float4(o[12], o[13], o[14], o[15]);
}

// ---------------------------------------------------------------------------
extern "C" void kernel_launch(void* const* d_in, const int* in_sizes, int n_in,
                              void* d_out, int out_size, void* d_ws, size_t ws_size,
                              hipStream_t stream)
{
  const float* x   = (const float*)d_in[0];
  const float* Wg  = (const float*)d_in[1];
  const float* bg  = (const float*)d_in[2];
  const float* W1  = (const float*)d_in[3];
  const float* b1  = (const float*)d_in[4];
  const float* g1  = (const float*)d_in[5];
  const float* be1 = (const float*)d_in[6];
  const float* W2  = (const float*)d_in[7];
  const float* b2  = (const float*)d_in[8];
  const float* g2  = (const float*)d_in[9];
  const float* be2 = (const float*)d_in[10];
  float* out = (float*)d_out;
  float* gate_out = out + (size_t)NT * H_DIM;

  char* ws = (char*)d_ws;
  size_t off = 0;
  auto alloc = [&](size_t bytes) { char* p = ws + off; off += (bytes + 255) & ~(size_t)255; return p; };
  unsigned short* w1bt = (unsigned short*)alloc((size_t)NE * H_DIM * H_DIM * 2);
  unsigned short* w2bt = (unsigned short*)alloc((size_t)NE * H_DIM * H_DIM * 2);
  unsigned short* buf1 = (unsigned short*)alloc((size_t)NP * H_DIM * 2);
  unsigned short* buf2 = (unsigned short*)alloc((size_t)NP * H_DIM * 2);
  int*   tk_e      = (int*)alloc((size_t)NP * 4);
  float* tk_w      = (float*)alloc((size_t)NP * 4);
  int*   pairTok   = (int*)alloc((size_t)NP * 4);
  int*   pairExp   = (int*)alloc((size_t)NP * 4);
  int*   slots     = (int*)alloc((size_t)NP * 4);
  int*   blockHist = (int*)alloc(64 * 8 * 4);
  int*   blockBase = (int*)alloc(64 * 8 * 4);
  int*   count     = (int*)alloc(8 * 4);
  int*   offs      = (int*)alloc(8 * 4);
  (void)in_sizes; (void)n_in; (void)out_size; (void)ws_size;

  // Xb (bf16 copy of X) aliases buf2: consumed by gemm1 before gemm2 writes buf2.
  unsigned short* Xb = buf2;

  transpose_convert_kernel<<<dim3(16, 16, 16), 256, 0, stream>>>(W1, W2, w1bt, w2bt);
  xgate_kernel<<<dim3(NT / 4), 256, 0, stream>>>(x, Wg, bg, Xb, gate_out, tk_e, tk_w);
  hist_kernel<<<dim3(64), 256, 0, stream>>>(tk_e, blockHist);
  scan_kernel<<<dim3(1), 64, 0, stream>>>(blockHist, blockBase, count, offs);
  place_kernel<<<dim3(64), 256, 0, stream>>>(tk_e, blockBase, pairTok, pairExp, slots);
  gemm_kernel<true><<<dim3(8, 128, 8), 256, 0, stream>>>(
      Xb, w1bt, b1, pairTok, count, offs, buf1);
  ln_relu_kernel<<<dim3(NP / 4), 256, 0, stream>>>(buf1, g1, be1, pairExp);
  gemm_kernel<false><<<dim3(8, 128, 8), 256, 0, stream>>>(
      buf1, w2bt, b2, pairTok, count, offs, buf2);
  combine_kernel<<<dim3(NT / 4), 256, 0, stream>>>(
      buf2, x, g2, be2, slots, tk_e, tk_w, out);
}

// Round 3
// 413.407 us; speedup vs baseline: 2.3024x; 1.0254x over previous
//
#include <hip/hip_runtime.h>
#include <cstdint>
#include <cstddef>

constexpr int H_DIM = 1024;
constexpr int NE    = 8;
constexpr int NT    = 16384;
constexpr int NP    = NT * 2;   // total (token, expert) pairs: exactly 2 per token

constexpr int BM = 256, BN = 256, BK = 64;
constexpr int NKT = H_DIM / BK;          // 16 K-tiles
constexpr int MAX_WG = NE * (NT / BM) * (H_DIM / BN);  // 8*64*4 = 2048

typedef __attribute__((ext_vector_type(8))) short          short8;
typedef __attribute__((ext_vector_type(8))) unsigned short ushort8;
typedef __attribute__((ext_vector_type(4))) float          f32x4;

__device__ __forceinline__ unsigned short f2bf(float f) {
  union { float f; uint32_t u; } c; c.f = f;
  uint32_t u = c.u;
  u = (u + 0x7fffu + ((u >> 16) & 1u)) >> 16;   // RNE
  return (unsigned short)u;
}
__device__ __forceinline__ float bf2f(unsigned short h) {
  union { uint32_t u; float f; } c; c.u = ((uint32_t)h) << 16;
  return c.f;
}

// async 16B global -> LDS (wave-uniform LDS base; lane auto-offset *16; global addr per-lane)
__device__ __forceinline__ void gload16(const unsigned short* g, unsigned short* l) {
  __builtin_amdgcn_global_load_lds((const __attribute__((address_space(1))) void*)g,
                                   (__attribute__((address_space(3))) void*)l, 16, 0, 0);
}

// ---------------------------------------------------------------------------
// W [E][H][H] (in,out) fp32  ->  T [E][H][H] (out,in) bf16   (LDS-tiled 64x64)
// ---------------------------------------------------------------------------
__global__ __launch_bounds__(256) void transpose_convert_kernel(
    const float* __restrict__ W1, const float* __restrict__ W2,
    unsigned short* __restrict__ T1, unsigned short* __restrict__ T2)
{
  __shared__ float tile[64][65];
  int zi = blockIdx.z;
  const float* W = (zi < 8) ? W1 : W2;
  unsigned short* T = (zi < 8) ? T1 : T2;
  int e  = zi & 7;
  int o0 = blockIdx.x * 64;
  int h0 = blockIdx.y * 64;
  int c  = threadIdx.x & 63;
  int r0 = (threadIdx.x >> 6) * 16;
  const float* src = W + ((size_t)e * H_DIM + h0) * H_DIM + o0;
#pragma unroll
  for (int i = 0; i < 16; ++i)
    tile[r0 + i][c] = src[(size_t)(r0 + i) * H_DIM + c];
  __syncthreads();
  unsigned short* dst = T + ((size_t)e * H_DIM + o0) * H_DIM + h0;
#pragma unroll
  for (int i = 0; i < 16; ++i)
    dst[(size_t)(r0 + i) * H_DIM + c] = f2bf(tile[c][r0 + i]);
}

// ---------------------------------------------------------------------------
// Fused: X fp32 -> Xb bf16  +  gating (softmax over 8, top-2, renorm).
// ---------------------------------------------------------------------------
__global__ __launch_bounds__(256) void xgate_kernel(
    const float* __restrict__ X, const float* __restrict__ Wg,
    const float* __restrict__ bg, unsigned short* __restrict__ Xb,
    float* __restrict__ gate_out, int* __restrict__ tk_e, float* __restrict__ tk_w)
{
  int wid = threadIdx.x >> 6, lane = threadIdx.x & 63;
  int n = blockIdx.x * 4 + wid;
  const float* xr = X + (size_t)n * H_DIM;

  const float4* xp = (const float4*)(xr + lane * 16);
  float4 f0 = xp[0], f1 = xp[1], f2 = xp[2], f3 = xp[3];
  float v[16] = {f0.x,f0.y,f0.z,f0.w, f1.x,f1.y,f1.z,f1.w,
                 f2.x,f2.y,f2.z,f2.w, f3.x,f3.y,f3.z,f3.w};

  ushort8 u0, u1;
#pragma unroll
  for (int j = 0; j < 8; ++j) { u0[j] = f2bf(v[j]); u1[j] = f2bf(v[8 + j]); }
  ushort8* xb = (ushort8*)(Xb + (size_t)n * H_DIM + lane * 16);
  xb[0] = u0; xb[1] = u1;

  float acc[8];
#pragma unroll
  for (int e = 0; e < 8; ++e) acc[e] = 0.f;
#pragma unroll
  for (int j = 0; j < 16; ++j) {
    int h = lane * 16 + j;
    const float4* wg = (const float4*)(Wg + (size_t)h * 8);
    float4 a = wg[0], b = wg[1];
    float xv = v[j];
    acc[0] += xv * a.x; acc[1] += xv * a.y; acc[2] += xv * a.z; acc[3] += xv * a.w;
    acc[4] += xv * b.x; acc[5] += xv * b.y; acc[6] += xv * b.z; acc[7] += xv * b.w;
  }
#pragma unroll
  for (int m = 1; m < 64; m <<= 1) {
#pragma unroll
    for (int e = 0; e < 8; ++e) acc[e] += __shfl_xor(acc[e], m);
  }
#pragma unroll
  for (int e = 0; e < 8; ++e) acc[e] += bg[e];

  float mx = acc[0];
#pragma unroll
  for (int e = 1; e < 8; ++e) mx = fmaxf(mx, acc[e]);
  float g[8], s = 0.f;
#pragma unroll
  for (int e = 0; e < 8; ++e) { g[e] = __expf(acc[e] - mx); s += g[e]; }
  float inv = 1.f / s;
#pragma unroll
  for (int e = 0; e < 8; ++e) g[e] *= inv;

  int e0 = 0; float b0 = g[0];
#pragma unroll
  for (int e = 1; e < 8; ++e) if (g[e] > b0) { b0 = g[e]; e0 = e; }
  int e1 = -1; float b1v = -1.f;
#pragma unroll
  for (int e = 0; e < 8; ++e) if (e != e0 && g[e] > b1v) { b1v = g[e]; e1 = e; }
  float s2 = b0 + b1v + 1e-9f;

  if (lane == 0) {
    float4* gp = (float4*)(gate_out + (size_t)n * 8);
    gp[0] = make_float4(g[0], g[1], g[2], g[3]);
    gp[1] = make_float4(g[4], g[5], g[6], g[7]);
    tk_e[2 * n] = e0; tk_e[2 * n + 1] = e1;
    tk_w[2 * n] = b0 / s2; tk_w[2 * n + 1] = b1v / s2;
  }
}

// ---------------------------------------------------------------------------
// Routing: block-hist -> scan -> block-place (+ worklist for the GEMM grid)
// ---------------------------------------------------------------------------
__global__ __launch_bounds__(256) void hist_kernel(
    const int* __restrict__ tk_e, int* __restrict__ blockHist)
{
  __shared__ int h[8];
  if (threadIdx.x < 8) h[threadIdx.x] = 0;
  __syncthreads();
  int i0 = blockIdx.x * 512 + threadIdx.x;
  atomicAdd(&h[tk_e[i0]], 1);
  atomicAdd(&h[tk_e[i0 + 256]], 1);
  __syncthreads();
  if (threadIdx.x < 8) blockHist[blockIdx.x * 8 + threadIdx.x] = h[threadIdx.x];
}

__global__ void scan_kernel(const int* __restrict__ blockHist,
                            int* __restrict__ blockBase,
                            int* __restrict__ count, int* __restrict__ offs)
{
  int e = threadIdx.x;
  if (e < 8) {
    int run = 0;
    for (int b = 0; b < 64; ++b) { blockBase[b * 8 + e] = run; run += blockHist[b * 8 + e]; }
    count[e] = run;
  }
  __syncthreads();
  if (threadIdx.x == 0) {
    int o = 0;
    for (int k = 0; k < 8; ++k) { offs[k] = o; o += count[k]; }
  }
  __syncthreads();
  if (e < 8) {
    int o = offs[e];
    for (int b = 0; b < 64; ++b) blockBase[b * 8 + e] += o;
  }
}

__global__ __launch_bounds__(256) void place_kernel(
    const int* __restrict__ tk_e, const int* __restrict__ blockBase,
    int* __restrict__ pairTok, int* __restrict__ pairExp, int* __restrict__ slots)
{
  __shared__ int cur[8];
  if (threadIdx.x < 8) cur[threadIdx.x] = blockBase[blockIdx.x * 8 + threadIdx.x];
  __syncthreads();
#pragma unroll
  for (int j = 0; j < 2; ++j) {
    int i = blockIdx.x * 512 + j * 256 + threadIdx.x;
    int e = tk_e[i];
    int s = atomicAdd(&cur[e], 1);
    pairTok[s] = i >> 1; pairExp[s] = e; slots[i] = s;
  }
}

// worklist: entries ordered (e, nt) outer, mt inner -> XCD chunking keeps one
// B col-panel (524 KB) L2-resident per XCD.
__global__ void worklist_kernel(const int* __restrict__ count,
                                int* __restrict__ wl, int* __restrict__ wlCount)
{
  __shared__ int nmt[8], ebase[8], totalS;
  if (threadIdx.x == 0) {
    int o = 0;
    for (int e = 0; e < 8; ++e) {
      nmt[e] = (count[e] + BM - 1) / BM;
      ebase[e] = o;
      o += nmt[e] * (H_DIM / BN);
    }
    totalS = o;
    wlCount[0] = o;
  }
  __syncthreads();
  int total = totalS;
  for (int i = threadIdx.x; i < total; i += blockDim.x) {
    int e = 0;
    while (e < 7 && i >= ebase[e + 1]) ++e;
    int loc = i - ebase[e];
    int nt = loc / nmt[e];
    int mt = loc - nt * nmt[e];
    wl[i] = (e << 20) | (nt << 16) | mt;
  }
}

// ---------------------------------------------------------------------------
// 8-phase 256x256x64 MFMA GEMM (T1+T2+T3+T4+T5), 512 threads = 8 waves (2Mx4N).
// LDS: A,B each [2 dbuf][2 half][128 rows][64 k] bf16 (st_16x32-swizzled
// logical layout, linear physical dest for global_load_lds; source address
// pre-permuted; ds_read applies the same involution).
// ---------------------------------------------------------------------------
template<bool GATHER>
__global__ __launch_bounds__(512, 2) void gemm8_kernel(
    const unsigned short* __restrict__ Ab,   // GATHER: Xb [NT][H]; else buf rows [NP][H]
    const unsigned short* __restrict__ Bt,   // [E][H(out)][H(in)] bf16
    const float* __restrict__ bias,          // [E][H]
    const int* __restrict__ pairTok,
    const int* __restrict__ count, const int* __restrict__ offs,
    const int* __restrict__ wl, const int* __restrict__ wlCount,
    unsigned short* __restrict__ Out)        // [NP][H] bf16
{
  __shared__ unsigned short As[2 * 2 * 8192];   // 64 KB
  __shared__ unsigned short Bs[2 * 2 * 8192];   // 64 KB

  const int total = wlCount[0];
  const int orig = blockIdx.x;
  if (orig >= total) return;
  // bijective XCD chunking (m204)
  const int qq = total >> 3, rr = total & 7;
  const int xcd = orig & 7, sub = orig >> 3;
  const int idx = (xcd < rr ? xcd * (qq + 1) : rr * (qq + 1) + (xcd - rr) * qq) + sub;
  const int ent = wl[idx];
  const int e = ent >> 20, ntb = (ent >> 16) & 15, mtb = ent & 0xffff;
  const int cnt = count[e], base = offs[e];

  const int tid = threadIdx.x;
  const int wid = tid >> 6, l = tid & 63;
  const int wr = wid >> 2, wc = wid & 3;

  // ---- staging source geometry (inverse st_16x32 swizzle on global addr) ----
  const int rih0 = (((tid >> 6)) >> 1) * 16 + ((tid >> 2) & 15);       // issue 0
  const int rih1 = ((8 + (tid >> 6)) >> 1) * 16 + ((tid >> 2) & 15);   // issue 1
  const int selem = ((tid >> 6) & 1) * 32 + (((tid & 3) * 8) ^ (((tid >> 5) & 1) << 4));

  const unsigned short* ap[4];
  const unsigned short* bp[4];
  {
    int g0 = mtb * 256 + rih0;       if (g0 >= cnt) g0 = cnt - 1;
    int g1 = mtb * 256 + rih1;       if (g1 >= cnt) g1 = cnt - 1;
    int g2 = mtb * 256 + 128 + rih0; if (g2 >= cnt) g2 = cnt - 1;
    int g3 = mtb * 256 + 128 + rih1; if (g3 >= cnt) g3 = cnt - 1;
    size_t r0, r1, r2, r3;
    if (GATHER) {
      r0 = (size_t)pairTok[base + g0]; r1 = (size_t)pairTok[base + g1];
      r2 = (size_t)pairTok[base + g2]; r3 = (size_t)pairTok[base + g3];
    } else {
      r0 = (size_t)(base + g0); r1 = (size_t)(base + g1);
      r2 = (size_t)(base + g2); r3 = (size_t)(base + g3);
    }
    ap[0] = Ab + r0 * H_DIM + selem;
    ap[1] = Ab + r1 * H_DIM + selem;
    ap[2] = Ab + r2 * H_DIM + selem;
    ap[3] = Ab + r3 * H_DIM + selem;
    const unsigned short* bbase = Bt + ((size_t)e * H_DIM + ntb * 256) * H_DIM + selem;
    bp[0] = bbase + (size_t)(rih0)       * H_DIM;
    bp[1] = bbase + (size_t)(rih1)       * H_DIM;
    bp[2] = bbase + (size_t)(128 + rih0) * H_DIM;
    bp[3] = bbase + (size_t)(128 + rih1) * H_DIM;
  }

  // LDS dest (shorts): wave-uniform base; lane auto-offset 16B
#define A_DST(t, h, i) (As + ((t) & 1) * 16384 + (h) * 8192 + (i) * 4096 + wid * 512)
#define B_DST(t, h, i) (Bs + ((t) & 1) * 16384 + (h) * 8192 + (i) * 4096 + wid * 512)

  // frag read lane offset within 1KB subtile (bytes), with st_16x32 XOR
  const int loff = ((l & 15) * 64 + (l >> 4) * 16) ^ (((l >> 3) & 1) << 5);
  const char* AsB = (const char*)As + wr * 16384 + loff;
  const char* BsB = (const char*)Bs + (wc >> 1) * 16384 + loff;
  const int bsub = (wc & 1) * 4;   // B subtile-row base for this wave

  // ---- prologue: tile0 (A0,A1,B0,B1) + tile1 (B0,B1); vmcnt(4); barrier ----
  gload16(ap[0], A_DST(0, 0, 0)); gload16(ap[1], A_DST(0, 0, 1));
  gload16(ap[2], A_DST(0, 1, 0)); gload16(ap[3], A_DST(0, 1, 1));
  gload16(bp[0], B_DST(0, 0, 0)); gload16(bp[1], B_DST(0, 0, 1));
  gload16(bp[2], B_DST(0, 1, 0)); gload16(bp[3], B_DST(0, 1, 1));
  gload16(bp[0] + BK, B_DST(1, 0, 0)); gload16(bp[1] + BK, B_DST(1, 0, 1));
  gload16(bp[2] + BK, B_DST(1, 1, 0)); gload16(bp[3] + BK, B_DST(1, 1, 1));
  asm volatile("s_waitcnt vmcnt(4)" ::: "memory");
  __builtin_amdgcn_s_barrier();

  f32x4 acc[8][4] = {};

  for (int t = 0; t < NKT; ++t) {
    const int db = t & 1;
    const int dboff = db * 32768;
    short8 bfrag[4][2];
#pragma unroll
    for (int q = 0; q < 4; ++q) {
      // ds-load this phase's A quadrant (and all B frags in phase 0)
      short8 af[2][2];
#pragma unroll
      for (int j = 0; j < 2; ++j)
#pragma unroll
        for (int ks = 0; ks < 2; ++ks)
          af[j][ks] = *(const short8*)(AsB + dboff + ((q * 2 + j) * 2 + ks) * 1024);
      if (q == 0) {
#pragma unroll
        for (int r = 0; r < 4; ++r)
#pragma unroll
          for (int ks = 0; ks < 2; ++ks)
            bfrag[r][ks] = *(const short8*)(BsB + dboff + ((bsub + r) * 2 + ks) * 1024);
      }
      // stage: A halves of t+1 at phases 0,1 (other buffer);
      //        B halves of t+2 at phases 2,3 (this buffer's B, read only in phase 0)
      if (q == 0 && t + 1 < NKT) {
        gload16(ap[0] + (t + 1) * BK, A_DST(t + 1, 0, 0));
        gload16(ap[1] + (t + 1) * BK, A_DST(t + 1, 0, 1));
      }
      if (q == 1 && t + 1 < NKT) {
        gload16(ap[2] + (t + 1) * BK, A_DST(t + 1, 1, 0));
        gload16(ap[3] + (t + 1) * BK, A_DST(t + 1, 1, 1));
      }
      if (q == 2 && t + 2 < NKT) {
        gload16(bp[0] + (t + 2) * BK, B_DST(t + 2, 0, 0));
        gload16(bp[1] + (t + 2) * BK, B_DST(t + 2, 0, 1));
      }
      if (q == 3 && t + 2 < NKT) {
        gload16(bp[2] + (t + 2) * BK, B_DST(t + 2, 1, 0));
        gload16(bp[3] + (t + 2) * BK, B_DST(t + 2, 1, 1));
      }
      __builtin_amdgcn_s_barrier();
      __builtin_amdgcn_s_setprio(1);
#pragma unroll
      for (int j = 0; j < 2; ++j)
#pragma unroll
        for (int r = 0; r < 4; ++r)
#pragma unroll
          for (int ks = 0; ks < 2; ++ks)
            acc[q * 2 + j][r] = __builtin_amdgcn_mfma_f32_16x16x32_bf16(
                af[j][ks], bfrag[r][ks], acc[q * 2 + j][r], 0, 0, 0);
      __builtin_amdgcn_s_setprio(0);
      if (q == 3) {
        if (t + 2 < NKT) asm volatile("s_waitcnt vmcnt(4)" ::: "memory");
        else             asm volatile("s_waitcnt vmcnt(0)" ::: "memory");
      }
      __builtin_amdgcn_s_barrier();
    }
  }

  // ---- epilogue: + bias, write bf16 ----
  float bvv[4];
#pragma unroll
  for (int r = 0; r < 4; ++r)
    bvv[r] = bias[e * H_DIM + ntb * 256 + wc * 64 + r * 16 + (l & 15)];
#pragma unroll
  for (int j = 0; j < 8; ++j) {
    int grow0 = mtb * 256 + wr * 128 + j * 16 + (l >> 4) * 4;
#pragma unroll
    for (int r = 0; r < 4; ++r) {
      int gcol = ntb * 256 + wc * 64 + r * 16 + (l & 15);
#pragma unroll
      for (int v = 0; v < 4; ++v) {
        int row = grow0 + v;
        if (row < cnt)
          Out[(size_t)(base + row) * H_DIM + gcol] = f2bf(acc[j][r][v] + bvv[r]);
      }
    }
  }
#undef A_DST
#undef B_DST
}

// ---------------------------------------------------------------------------
// In-place relu(LayerNorm(row)) on bf16 rows; one wave per row.
// ---------------------------------------------------------------------------
__global__ __launch_bounds__(256) void ln_relu_kernel(
    unsigned short* __restrict__ buf, const float* __restrict__ gamma,
    const float* __restrict__ beta, const int* __restrict__ pairExp)
{
  int wid = threadIdx.x >> 6, lane = threadIdx.x & 63;
  int row = blockIdx.x * 4 + wid;
  int e = pairExp[row];
  unsigned short* r = buf + (size_t)row * H_DIM;
  ushort8 u0 = ((const ushort8*)r)[lane];
  ushort8 u1 = ((const ushort8*)r)[lane + 64];
  float v[16];
#pragma unroll
  for (int j = 0; j < 8; ++j) { v[j] = bf2f(u0[j]); v[8 + j] = bf2f(u1[j]); }
  float s = 0.f, ss = 0.f;
#pragma unroll
  for (int j = 0; j < 16; ++j) { s += v[j]; ss += v[j] * v[j]; }
#pragma unroll
  for (int m = 1; m < 64; m <<= 1) { s += __shfl_xor(s, m); ss += __shfl_xor(ss, m); }
  float mean = s * (1.f / 1024.f);
  float var  = ss * (1.f / 1024.f) - mean * mean;
  float rs   = rsqrtf(var + 1e-5f);

  int h0 = lane * 8, h1 = 512 + lane * 8;
  const float4* gp0 = (const float4*)(gamma + (size_t)e * H_DIM + h0);
  const float4* bp0 = (const float4*)(beta  + (size_t)e * H_DIM + h0);
  const float4* gp1 = (const float4*)(gamma + (size_t)e * H_DIM + h1);
  const float4* bp1 = (const float4*)(beta  + (size_t)e * H_DIM + h1);
  float4 ga = gp0[0], gb = gp0[1], gc = gp1[0], gd = gp1[1];
  float4 ba = bp0[0], bb = bp0[1], bc = bp1[0], bd = bp1[1];
  float gv[16] = {ga.x,ga.y,ga.z,ga.w, gb.x,gb.y,gb.z,gb.w,
                  gc.x,gc.y,gc.z,gc.w, gd.x,gd.y,gd.z,gd.w};
  float bv[16] = {ba.x,ba.y,ba.z,ba.w, bb.x,bb.y,bb.z,bb.w,
                  bc.x,bc.y,bc.z,bc.w, bd.x,bd.y,bd.z,bd.w};
#pragma unroll
  for (int j = 0; j < 8; ++j) {
    float t0 = fmaxf((v[j]     - mean) * rs * gv[j]     + bv[j],     0.f);
    float t1 = fmaxf((v[8 + j] - mean) * rs * gv[8 + j] + bv[8 + j], 0.f);
    u0[j] = f2bf(t0); u1[j] = f2bf(t1);
  }
  ((ushort8*)r)[lane] = u0; ((ushort8*)r)[lane + 64] = u1;
}

// ---------------------------------------------------------------------------
// Combine: per token, LN2 each of its 2 expert rows, y=relu(x+u), out = sum w*y
// ---------------------------------------------------------------------------
__global__ __launch_bounds__(256) void combine_kernel(
    const unsigned short* __restrict__ buf2, const float* __restrict__ X,
    const float* __restrict__ g2, const float* __restrict__ be2,
    const int* __restrict__ slots, const int* __restrict__ tk_e,
    const float* __restrict__ tk_w, float* __restrict__ out)
{
  int wid = threadIdx.x >> 6, lane = threadIdx.x & 63;
  int n = blockIdx.x * 4 + wid;
  int h0 = lane * 8, h1 = 512 + lane * 8;

  const float4* xp0 = (const float4*)(X + (size_t)n * H_DIM + h0);
  const float4* xp1 = (const float4*)(X + (size_t)n * H_DIM + h1);
  float4 xa = xp0[0], xb = xp0[1], xc = xp1[0], xd = xp1[1];
  float xv[16] = {xa.x,xa.y,xa.z,xa.w, xb.x,xb.y,xb.z,xb.w,
                  xc.x,xc.y,xc.z,xc.w, xd.x,xd.y,xd.z,xd.w};
  float o[16];
#pragma unroll
  for (int j = 0; j < 16; ++j) o[j] = 0.f;

#pragma unroll
  for (int k = 0; k < 2; ++k) {
    int slot = slots[2 * n + k];
    int e = tk_e[2 * n + k];
    float w = tk_w[2 * n + k];
    const unsigned short* r = buf2 + (size_t)slot * H_DIM;
    ushort8 u0 = ((const ushort8*)r)[lane];
    ushort8 u1 = ((const ushort8*)r)[lane + 64];
    float v[16];
#pragma unroll
    for (int j = 0; j < 8; ++j) { v[j] = bf2f(u0[j]); v[8 + j] = bf2f(u1[j]); }
    float s = 0.f, ss = 0.f;
#pragma unroll
    for (int j = 0; j < 16; ++j) { s += v[j]; ss += v[j] * v[j]; }
#pragma unroll
    for (int m = 1; m < 64; m <<= 1) { s += __shfl_xor(s, m); ss += __shfl_xor(ss, m); }
    float mean = s * (1.f / 1024.f);
    float var  = ss * (1.f / 1024.f) - mean * mean;
    float rs   = rsqrtf(var + 1e-5f);

    const float4* gp0 = (const float4*)(g2  + (size_t)e * H_DIM + h0);
    const float4* bp0 = (const float4*)(be2 + (size_t)e * H_DIM + h0);
    const float4* gp1 = (const float4*)(g2  + (size_t)e * H_DIM + h1);
    const float4* bp1 = (const float4*)(be2 + (size_t)e * H_DIM + h1);
    float4 ga = gp0[0], gb = gp0[1], gc = gp1[0], gd = gp1[1];
    float4 ba = bp0[0], bb = bp0[1], bc = bp1[0], bd = bp1[1];
    float gv[16] = {ga.x,ga.y,ga.z,ga.w, gb.x,gb.y,gb.z,gb.w,
                    gc.x,gc.y,gc.z,gc.w, gd.x,gd.y,gd.z,gd.w};
    float bvv[16] = {ba.x,ba.y,ba.z,ba.w, bb.x,bb.y,bb.z,bb.w,
                     bc.x,bc.y,bc.z,bc.w, bd.x,bd.y,bd.z,bd.w};
#pragma unroll
    for (int j = 0; j < 16; ++j) {
      float u = (v[j] - mean) * rs * gv[j] + bvv[j];
      float y = fmaxf(xv[j] + u, 0.f);
      o[j] += w * y;
    }
  }

  float4* op0 = (float4*)(out + (size_t)n * H_DIM + h0);
  float4* op1 = (float4*)(out + (size_t)n * H_DIM + h1);
  op0[0] = make_float4(o[0], o[1], o[2], o[3]);
  op0[1] = make_float4(o[4], o[5], o[6], o[7]);
  op1[0] = make_float4(o[8], o[9], o[10], o[11]);
  op1[1] = make_float4(o[12], o[13], o[14], o[15]);
}

// ---------------------------------------------------------------------------
extern "C" void kernel_launch(void* const* d_in, const int* in_sizes, int n_in,
                              void* d_out, int out_size, void* d_ws, size_t ws_size,
                              hipStream_t stream)
{
  const float* x   = (const float*)d_in[0];
  const float* Wg  = (const float*)d_in[1];
  const float* bg  = (const float*)d_in[2];
  const float* W1  = (const float*)d_in[3];
  const float* b1  = (const float*)d_in[4];
  const float* g1  = (const float*)d_in[5];
  const float* be1 = (const float*)d_in[6];
  const float* W2  = (const float*)d_in[7];
  const float* b2  = (const float*)d_in[8];
  const float* g2  = (const float*)d_in[9];
  const float* be2 = (const float*)d_in[10];
  float* out = (float*)d_out;
  float* gate_out = out + (size_t)NT * H_DIM;

  char* ws = (char*)d_ws;
  size_t off = 0;
  auto alloc = [&](size_t bytes) { char* p = ws + off; off += (bytes + 255) & ~(size_t)255; return p; };
  unsigned short* w1bt = (unsigned short*)alloc((size_t)NE * H_DIM * H_DIM * 2);
  unsigned short* w2bt = (unsigned short*)alloc((size_t)NE * H_DIM * H_DIM * 2);
  unsigned short* buf1 = (unsigned short*)alloc((size_t)NP * H_DIM * 2);
  unsigned short* buf2 = (unsigned short*)alloc((size_t)NP * H_DIM * 2);
  int*   tk_e      = (int*)alloc((size_t)NP * 4);
  float* tk_w      = (float*)alloc((size_t)NP * 4);
  int*   pairTok   = (int*)alloc((size_t)NP * 4);
  int*   pairExp   = (int*)alloc((size_t)NP * 4);
  int*   slots     = (int*)alloc((size_t)NP * 4);
  int*   blockHist = (int*)alloc(64 * 8 * 4);
  int*   blockBase = (int*)alloc(64 * 8 * 4);
  int*   count     = (int*)alloc(8 * 4);
  int*   offs      = (int*)alloc(8 * 4);
  int*   wl        = (int*)alloc(MAX_WG * 4);
  int*   wlCount   = (int*)alloc(4);
  (void)in_sizes; (void)n_in; (void)out_size; (void)ws_size;

  // Xb (bf16 copy of X) aliases buf2: consumed by gemm1 before gemm2 writes buf2.
  unsigned short* Xb = buf2;

  transpose_convert_kernel<<<dim3(16, 16, 16), 256, 0, stream>>>(W1, W2, w1bt, w2bt);
  xgate_kernel<<<dim3(NT / 4), 256, 0, stream>>>(x, Wg, bg, Xb, gate_out, tk_e, tk_w);
  hist_kernel<<<dim3(64), 256, 0, stream>>>(tk_e, blockHist);
  scan_kernel<<<dim3(1), 64, 0, stream>>>(blockHist, blockBase, count, offs);
  worklist_kernel<<<dim3(1), 256, 0, stream>>>(count, wl, wlCount);
  place_kernel<<<dim3(64), 256, 0, stream>>>(tk_e, blockBase, pairTok, pairExp, slots);
  gemm8_kernel<true><<<dim3(MAX_WG), 512, 0, stream>>>(
      Xb, w1bt, b1, pairTok, count, offs, wl, wlCount, buf1);
  ln_relu_kernel<<<dim3(NP / 4), 256, 0, stream>>>(buf1, g1, be1, pairExp);
  gemm8_kernel<false><<<dim3(MAX_WG), 512, 0, stream>>>(
      buf1, w2bt, b2, pairTok, count, offs, wl, wlCount, buf2);
  combine_kernel<<<dim3(NT / 4), 256, 0, stream>>>(
      buf2, x, g2, be2, slots, tk_e, tk_w, out);
}

// Round 4
// 368.058 us; speedup vs baseline: 2.5860x; 1.1232x over previous
//
#include <hip/hip_runtime.h>
#include <cstdint>
#include <cstddef>

constexpr int H_DIM = 1024;
constexpr int NE    = 8;
constexpr int NT    = 16384;
constexpr int NP    = NT * 2;   // total (token, expert) pairs: exactly 2 per token

constexpr int BM = 256, BN = 256, BK = 32;
constexpr int NKT = H_DIM / BK;          // 32 K-tiles
constexpr int MAX_WG = NE * (NT / BM) * (H_DIM / BN);  // 2048

typedef __attribute__((ext_vector_type(8))) short          short8;
typedef __attribute__((ext_vector_type(8))) unsigned short ushort8;
typedef __attribute__((ext_vector_type(4))) float          f32x4;

__device__ __forceinline__ unsigned short f2bf(float f) {
  union { float f; uint32_t u; } c; c.f = f;
  uint32_t u = c.u;
  u = (u + 0x7fffu + ((u >> 16) & 1u)) >> 16;   // RNE
  return (unsigned short)u;
}
__device__ __forceinline__ float bf2f(unsigned short h) {
  union { uint32_t u; float f; } c; c.u = ((uint32_t)h) << 16;
  return c.f;
}

// async 16B global -> LDS (wave-uniform LDS base; lane auto-offset *16; global addr per-lane)
__device__ __forceinline__ void gload16(const unsigned short* g, unsigned short* l) {
  __builtin_amdgcn_global_load_lds((const __attribute__((address_space(1))) void*)g,
                                   (__attribute__((address_space(3))) void*)l, 16, 0, 0);
}

// ---------------------------------------------------------------------------
// W [E][H][H] (in,out) fp32  ->  T [E][H][H] (out,in) bf16   (LDS-tiled 64x64)
// ---------------------------------------------------------------------------
__global__ __launch_bounds__(256) void transpose_convert_kernel(
    const float* __restrict__ W1, const float* __restrict__ W2,
    unsigned short* __restrict__ T1, unsigned short* __restrict__ T2)
{
  __shared__ float tile[64][65];
  int zi = blockIdx.z;
  const float* W = (zi < 8) ? W1 : W2;
  unsigned short* T = (zi < 8) ? T1 : T2;
  int e  = zi & 7;
  int o0 = blockIdx.x * 64;
  int h0 = blockIdx.y * 64;
  int c  = threadIdx.x & 63;
  int r0 = (threadIdx.x >> 6) * 16;
  const float* src = W + ((size_t)e * H_DIM + h0) * H_DIM + o0;
#pragma unroll
  for (int i = 0; i < 16; ++i)
    tile[r0 + i][c] = src[(size_t)(r0 + i) * H_DIM + c];
  __syncthreads();
  unsigned short* dst = T + ((size_t)e * H_DIM + o0) * H_DIM + h0;
#pragma unroll
  for (int i = 0; i < 16; ++i)
    dst[(size_t)(r0 + i) * H_DIM + c] = f2bf(tile[c][r0 + i]);
}

// ---------------------------------------------------------------------------
// Fused: X fp32 -> Xb bf16  +  gating (softmax over 8, top-2, renorm).
// ---------------------------------------------------------------------------
__global__ __launch_bounds__(256) void xgate_kernel(
    const float* __restrict__ X, const float* __restrict__ Wg,
    const float* __restrict__ bg, unsigned short* __restrict__ Xb,
    float* __restrict__ gate_out, int* __restrict__ tk_e, float* __restrict__ tk_w)
{
  int wid = threadIdx.x >> 6, lane = threadIdx.x & 63;
  int n = blockIdx.x * 4 + wid;
  const float* xr = X + (size_t)n * H_DIM;

  const float4* xp = (const float4*)(xr + lane * 16);
  float4 f0 = xp[0], f1 = xp[1], f2 = xp[2], f3 = xp[3];
  float v[16] = {f0.x,f0.y,f0.z,f0.w, f1.x,f1.y,f1.z,f1.w,
                 f2.x,f2.y,f2.z,f2.w, f3.x,f3.y,f3.z,f3.w};

  ushort8 u0, u1;
#pragma unroll
  for (int j = 0; j < 8; ++j) { u0[j] = f2bf(v[j]); u1[j] = f2bf(v[8 + j]); }
  ushort8* xb = (ushort8*)(Xb + (size_t)n * H_DIM + lane * 16);
  xb[0] = u0; xb[1] = u1;

  float acc[8];
#pragma unroll
  for (int e = 0; e < 8; ++e) acc[e] = 0.f;
#pragma unroll
  for (int j = 0; j < 16; ++j) {
    int h = lane * 16 + j;
    const float4* wg = (const float4*)(Wg + (size_t)h * 8);
    float4 a = wg[0], b = wg[1];
    float xv = v[j];
    acc[0] += xv * a.x; acc[1] += xv * a.y; acc[2] += xv * a.z; acc[3] += xv * a.w;
    acc[4] += xv * b.x; acc[5] += xv * b.y; acc[6] += xv * b.z; acc[7] += xv * b.w;
  }
#pragma unroll
  for (int m = 1; m < 64; m <<= 1) {
#pragma unroll
    for (int e = 0; e < 8; ++e) acc[e] += __shfl_xor(acc[e], m);
  }
#pragma unroll
  for (int e = 0; e < 8; ++e) acc[e] += bg[e];

  float mx = acc[0];
#pragma unroll
  for (int e = 1; e < 8; ++e) mx = fmaxf(mx, acc[e]);
  float g[8], s = 0.f;
#pragma unroll
  for (int e = 0; e < 8; ++e) { g[e] = __expf(acc[e] - mx); s += g[e]; }
  float inv = 1.f / s;
#pragma unroll
  for (int e = 0; e < 8; ++e) g[e] *= inv;

  int e0 = 0; float b0 = g[0];
#pragma unroll
  for (int e = 1; e < 8; ++e) if (g[e] > b0) { b0 = g[e]; e0 = e; }
  int e1 = -1; float b1v = -1.f;
#pragma unroll
  for (int e = 0; e < 8; ++e) if (e != e0 && g[e] > b1v) { b1v = g[e]; e1 = e; }
  float s2 = b0 + b1v + 1e-9f;

  if (lane == 0) {
    float4* gp = (float4*)(gate_out + (size_t)n * 8);
    gp[0] = make_float4(g[0], g[1], g[2], g[3]);
    gp[1] = make_float4(g[4], g[5], g[6], g[7]);
    tk_e[2 * n] = e0; tk_e[2 * n + 1] = e1;
    tk_w[2 * n] = b0 / s2; tk_w[2 * n + 1] = b1v / s2;
  }
}

// ---------------------------------------------------------------------------
// Routing: block-hist -> scan -> block-place (+ worklist for the GEMM grid)
// ---------------------------------------------------------------------------
__global__ __launch_bounds__(256) void hist_kernel(
    const int* __restrict__ tk_e, int* __restrict__ blockHist)
{
  __shared__ int h[8];
  if (threadIdx.x < 8) h[threadIdx.x] = 0;
  __syncthreads();
  int i0 = blockIdx.x * 512 + threadIdx.x;
  atomicAdd(&h[tk_e[i0]], 1);
  atomicAdd(&h[tk_e[i0 + 256]], 1);
  __syncthreads();
  if (threadIdx.x < 8) blockHist[blockIdx.x * 8 + threadIdx.x] = h[threadIdx.x];
}

__global__ void scan_kernel(const int* __restrict__ blockHist,
                            int* __restrict__ blockBase,
                            int* __restrict__ count, int* __restrict__ offs)
{
  int e = threadIdx.x;
  if (e < 8) {
    int run = 0;
    for (int b = 0; b < 64; ++b) { blockBase[b * 8 + e] = run; run += blockHist[b * 8 + e]; }
    count[e] = run;
  }
  __syncthreads();
  if (threadIdx.x == 0) {
    int o = 0;
    for (int k = 0; k < 8; ++k) { offs[k] = o; o += count[k]; }
  }
  __syncthreads();
  if (e < 8) {
    int o = offs[e];
    for (int b = 0; b < 64; ++b) blockBase[b * 8 + e] += o;
  }
}

__global__ __launch_bounds__(256) void place_kernel(
    const int* __restrict__ tk_e, const int* __restrict__ blockBase,
    int* __restrict__ pairTok, int* __restrict__ pairExp, int* __restrict__ slots)
{
  __shared__ int cur[8];
  if (threadIdx.x < 8) cur[threadIdx.x] = blockBase[blockIdx.x * 8 + threadIdx.x];
  __syncthreads();
#pragma unroll
  for (int j = 0; j < 2; ++j) {
    int i = blockIdx.x * 512 + j * 256 + threadIdx.x;
    int e = tk_e[i];
    int s = atomicAdd(&cur[e], 1);
    pairTok[s] = i >> 1; pairExp[s] = e; slots[i] = s;
  }
}

// worklist ordered (e, nt) outer, mt inner -> XCD chunking keeps one B col-panel
// L2-resident per XCD.
__global__ void worklist_kernel(const int* __restrict__ count,
                                int* __restrict__ wl, int* __restrict__ wlCount)
{
  __shared__ int nmt[8], ebase[8], totalS;
  if (threadIdx.x == 0) {
    int o = 0;
    for (int e = 0; e < 8; ++e) {
      nmt[e] = (count[e] + BM - 1) / BM;
      ebase[e] = o;
      o += nmt[e] * (H_DIM / BN);
    }
    totalS = o;
    wlCount[0] = o;
  }
  __syncthreads();
  int total = totalS;
  for (int i = threadIdx.x; i < total; i += blockDim.x) {
    int e = 0;
    while (e < 7 && i >= ebase[e + 1]) ++e;
    int loc = i - ebase[e];
    int nt = loc / nmt[e];
    int mt = loc - nt * nmt[e];
    wl[i] = (e << 20) | (nt << 16) | mt;
  }
}

// ---------------------------------------------------------------------------
// 256x256xBK32 MFMA GEMM, 4-deep LDS ring (slot = t&3), ONE barrier per K-tile,
// counted vmcnt(8) (loads issued 3 tiles ahead of their drain). st_16x32
// swizzle via pre-permuted global source + XOR'd ds_read. 8 waves (2M x 4N).
// ---------------------------------------------------------------------------
template<bool GATHER>
__global__ __launch_bounds__(512, 2) void gemm4_kernel(
    const unsigned short* __restrict__ Ab,   // GATHER: Xb [NT][H]; else buf rows [NP][H]
    const unsigned short* __restrict__ Bt,   // [E][H(out)][H(in)] bf16
    const float* __restrict__ bias,          // [E][H]
    const int* __restrict__ pairTok,
    const int* __restrict__ count, const int* __restrict__ offs,
    const int* __restrict__ wl, const int* __restrict__ wlCount,
    unsigned short* __restrict__ Out)        // [NP][H] bf16
{
  __shared__ unsigned short As[4 * 8192];   // 64 KB: 4 slots x (256 rows x 32 k)
  __shared__ unsigned short Bs[4 * 8192];   // 64 KB

  const int total = wlCount[0];
  const int orig = blockIdx.x;
  if (orig >= total) return;
  // bijective XCD chunking (m204)
  const int qq = total >> 3, rr = total & 7;
  const int xcd = orig & 7, sub = orig >> 3;
  const int idx = (xcd < rr ? xcd * (qq + 1) : rr * (qq + 1) + (xcd - rr) * qq) + sub;
  const int ent = wl[idx];
  const int e = ent >> 20, ntb = (ent >> 16) & 15, mtb = ent & 0xffff;
  const int cnt = count[e], base = offs[e];

  const int tid = threadIdx.x;
  const int wid = tid >> 6, l = tid & 63;
  const int wr = wid >> 2, wc = wid & 3;

  // ---- staging source geometry ----
  // subtile s = issue*8 + wid covers rows [s*16, s*16+16); lane: row += l>>2,
  // k-chunk (l&3)*8 XOR'd by row-bit3 (st_16x32 involution, pre-applied to src)
  const int rsub = (l >> 2);
  const int kswz = ((l & 3) * 8) ^ (((l >> 5) & 1) << 4);

  const unsigned short *apg0, *apg1, *bpg0, *bpg1;
  {
    int r0 = wid * 16 + rsub;          // issue 0 rows [0,128)
    int r1 = 128 + wid * 16 + rsub;    // issue 1 rows [128,256)
    int g0 = mtb * 256 + r0; if (g0 >= cnt) g0 = cnt - 1;
    int g1 = mtb * 256 + r1; if (g1 >= cnt) g1 = cnt - 1;
    size_t a0, a1;
    if (GATHER) { a0 = (size_t)pairTok[base + g0]; a1 = (size_t)pairTok[base + g1]; }
    else        { a0 = (size_t)(base + g0);        a1 = (size_t)(base + g1); }
    apg0 = Ab + a0 * H_DIM + kswz;
    apg1 = Ab + a1 * H_DIM + kswz;
    const unsigned short* bb = Bt + ((size_t)e * H_DIM + ntb * 256) * H_DIM + kswz;
    bpg0 = bb + (size_t)r0 * H_DIM;
    bpg1 = bb + (size_t)r1 * H_DIM;
  }

  // frag-read byte offset within 1KB subtile, same XOR involution
  const int loff = ((l & 15) * 64 + (l >> 4) * 16) ^ (((l >> 3) & 1) << 5);

  auto STAGE = [&](int u) {
    int sl = u & 3;
    unsigned short* ad = As + sl * 8192 + wid * 512;
    unsigned short* bd = Bs + sl * 8192 + wid * 512;
    gload16(apg0 + (size_t)u * BK, ad);
    gload16(apg1 + (size_t)u * BK, ad + 4096);
    gload16(bpg0 + (size_t)u * BK, bd);
    gload16(bpg1 + (size_t)u * BK, bd + 4096);
  };

  // ---- prologue: stage tiles 0..2; ensure tile 0 done ----
  STAGE(0); STAGE(1); STAGE(2);
  asm volatile("s_waitcnt vmcnt(8)" ::: "memory");
  __builtin_amdgcn_s_barrier();

  f32x4 acc[8][4] = {};

#pragma unroll 4
  for (int t = 0; t < NKT; ++t) {
    const int sl = t & 3;
    const char* aB = (const char*)As + sl * 16384 + wr * 8192 + loff;
    const char* bB = (const char*)Bs + sl * 16384 + wc * 4096 + loff;

    short8 af[8], bfr[4];
#pragma unroll
    for (int j = 0; j < 8; ++j) af[j] = *(const short8*)(aB + j * 1024);
#pragma unroll
    for (int r = 0; r < 4; ++r) bfr[r] = *(const short8*)(bB + r * 1024);

    if (t <= NKT - 4) STAGE(t + 3);

    __builtin_amdgcn_s_setprio(1);
#pragma unroll
    for (int j = 0; j < 8; ++j)
#pragma unroll
      for (int r = 0; r < 4; ++r)
        acc[j][r] = __builtin_amdgcn_mfma_f32_16x16x32_bf16(af[j], bfr[r], acc[j][r], 0, 0, 0);
    __builtin_amdgcn_s_setprio(0);

    if (t <= NKT - 4)      asm volatile("s_waitcnt vmcnt(8)" ::: "memory");
    else if (t == NKT - 3) asm volatile("s_waitcnt vmcnt(4)" ::: "memory");
    else if (t == NKT - 2) asm volatile("s_waitcnt vmcnt(0)" ::: "memory");
    __builtin_amdgcn_s_barrier();
  }

  // ---- epilogue: + bias, write bf16 ----
  float bvv[4];
#pragma unroll
  for (int r = 0; r < 4; ++r)
    bvv[r] = bias[e * H_DIM + ntb * 256 + wc * 64 + r * 16 + (l & 15)];
#pragma unroll
  for (int j = 0; j < 8; ++j) {
    int grow0 = mtb * 256 + wr * 128 + j * 16 + (l >> 4) * 4;
#pragma unroll
    for (int r = 0; r < 4; ++r) {
      int gcol = ntb * 256 + wc * 64 + r * 16 + (l & 15);
#pragma unroll
      for (int v = 0; v < 4; ++v) {
        int row = grow0 + v;
        if (row < cnt)
          Out[(size_t)(base + row) * H_DIM + gcol] = f2bf(acc[j][r][v] + bvv[r]);
      }
    }
  }
}

// ---------------------------------------------------------------------------
// In-place relu(LayerNorm(row)) on bf16 rows; one wave per row.
// ---------------------------------------------------------------------------
__global__ __launch_bounds__(256) void ln_relu_kernel(
    unsigned short* __restrict__ buf, const float* __restrict__ gamma,
    const float* __restrict__ beta, const int* __restrict__ pairExp)
{
  int wid = threadIdx.x >> 6, lane = threadIdx.x & 63;
  int row = blockIdx.x * 4 + wid;
  int e = pairExp[row];
  unsigned short* r = buf + (size_t)row * H_DIM;
  ushort8 u0 = ((const ushort8*)r)[lane];
  ushort8 u1 = ((const ushort8*)r)[lane + 64];
  float v[16];
#pragma unroll
  for (int j = 0; j < 8; ++j) { v[j] = bf2f(u0[j]); v[8 + j] = bf2f(u1[j]); }
  float s = 0.f, ss = 0.f;
#pragma unroll
  for (int j = 0; j < 16; ++j) { s += v[j]; ss += v[j] * v[j]; }
#pragma unroll
  for (int m = 1; m < 64; m <<= 1) { s += __shfl_xor(s, m); ss += __shfl_xor(ss, m); }
  float mean = s * (1.f / 1024.f);
  float var  = ss * (1.f / 1024.f) - mean * mean;
  float rs   = rsqrtf(var + 1e-5f);

  int h0 = lane * 8, h1 = 512 + lane * 8;
  const float4* gp0 = (const float4*)(gamma + (size_t)e * H_DIM + h0);
  const float4* bp0 = (const float4*)(beta  + (size_t)e * H_DIM + h0);
  const float4* gp1 = (const float4*)(gamma + (size_t)e * H_DIM + h1);
  const float4* bp1 = (const float4*)(beta  + (size_t)e * H_DIM + h1);
  float4 ga = gp0[0], gb = gp0[1], gc = gp1[0], gd = gp1[1];
  float4 ba = bp0[0], bb = bp0[1], bc = bp1[0], bd = bp1[1];
  float gv[16] = {ga.x,ga.y,ga.z,ga.w, gb.x,gb.y,gb.z,gb.w,
                  gc.x,gc.y,gc.z,gc.w, gd.x,gd.y,gd.z,gd.w};
  float bv[16] = {ba.x,ba.y,ba.z,ba.w, bb.x,bb.y,bb.z,bb.w,
                  bc.x,bc.y,bc.z,bc.w, bd.x,bd.y,bd.z,bd.w};
#pragma unroll
  for (int j = 0; j < 8; ++j) {
    float t0 = fmaxf((v[j]     - mean) * rs * gv[j]     + bv[j],     0.f);
    float t1 = fmaxf((v[8 + j] - mean) * rs * gv[8 + j] + bv[8 + j], 0.f);
    u0[j] = f2bf(t0); u1[j] = f2bf(t1);
  }
  ((ushort8*)r)[lane] = u0; ((ushort8*)r)[lane + 64] = u1;
}

// ---------------------------------------------------------------------------
// Combine: per token, LN2 each of its 2 expert rows, y=relu(x+u), out = sum w*y
// ---------------------------------------------------------------------------
__global__ __launch_bounds__(256) void combine_kernel(
    const unsigned short* __restrict__ buf2, const float* __restrict__ X,
    const float* __restrict__ g2, const float* __restrict__ be2,
    const int* __restrict__ slots, const int* __restrict__ tk_e,
    const float* __restrict__ tk_w, float* __restrict__ out)
{
  int wid = threadIdx.x >> 6, lane = threadIdx.x & 63;
  int n = blockIdx.x * 4 + wid;
  int h0 = lane * 8, h1 = 512 + lane * 8;

  const float4* xp0 = (const float4*)(X + (size_t)n * H_DIM + h0);
  const float4* xp1 = (const float4*)(X + (size_t)n * H_DIM + h1);
  float4 xa = xp0[0], xb = xp0[1], xc = xp1[0], xd = xp1[1];
  float xv[16] = {xa.x,xa.y,xa.z,xa.w, xb.x,xb.y,xb.z,xb.w,
                  xc.x,xc.y,xc.z,xc.w, xd.x,xd.y,xd.z,xd.w};
  float o[16];
#pragma unroll
  for (int j = 0; j < 16; ++j) o[j] = 0.f;

#pragma unroll
  for (int k = 0; k < 2; ++k) {
    int slot = slots[2 * n + k];
    int e = tk_e[2 * n + k];
    float w = tk_w[2 * n + k];
    const unsigned short* r = buf2 + (size_t)slot * H_DIM;
    ushort8 u0 = ((const ushort8*)r)[lane];
    ushort8 u1 = ((const ushort8*)r)[lane + 64];
    float v[16];
#pragma unroll
    for (int j = 0; j < 8; ++j) { v[j] = bf2f(u0[j]); v[8 + j] = bf2f(u1[j]); }
    float s = 0.f, ss = 0.f;
#pragma unroll
    for (int j = 0; j < 16; ++j) { s += v[j]; ss += v[j] * v[j]; }
#pragma unroll
    for (int m = 1; m < 64; m <<= 1) { s += __shfl_xor(s, m); ss += __shfl_xor(ss, m); }
    float mean = s * (1.f / 1024.f);
    float var  = ss * (1.f / 1024.f) - mean * mean;
    float rs   = rsqrtf(var + 1e-5f);

    const float4* gp0 = (const float4*)(g2  + (size_t)e * H_DIM + h0);
    const float4* bp0 = (const float4*)(be2 + (size_t)e * H_DIM + h0);
    const float4* gp1 = (const float4*)(g2  + (size_t)e * H_DIM + h1);
    const float4* bp1 = (const float4*)(be2 + (size_t)e * H_DIM + h1);
    float4 ga = gp0[0], gb = gp0[1], gc = gp1[0], gd = gp1[1];
    float4 ba = bp0[0], bb = bp0[1], bc = bp1[0], bd = bp1[1];
    float gv[16] = {ga.x,ga.y,ga.z,ga.w, gb.x,gb.y,gb.z,gb.w,
                    gc.x,gc.y,gc.z,gc.w, gd.x,gd.y,gd.z,gd.w};
    float bvv[16] = {ba.x,ba.y,ba.z,ba.w, bb.x,bb.y,bb.z,bb.w,
                     bc.x,bc.y,bc.z,bc.w, bd.x,bd.y,bd.z,bd.w};
#pragma unroll
    for (int j = 0; j < 16; ++j) {
      float u = (v[j] - mean) * rs * gv[j] + bvv[j];
      float y = fmaxf(xv[j] + u, 0.f);
      o[j] += w * y;
    }
  }

  float4* op0 = (float4*)(out + (size_t)n * H_DIM + h0);
  float4* op1 = (float4*)(out + (size_t)n * H_DIM + h1);
  op0[0] = make_float4(o[0], o[1], o[2], o[3]);
  op0[1] = make_float4(o[4], o[5], o[6], o[7]);
  op1[0] = make_float4(o[8], o[9], o[10], o[11]);
  op1[1] = make_float4(o[12], o[13], o[14], o[15]);
}

// ---------------------------------------------------------------------------
extern "C" void kernel_launch(void* const* d_in, const int* in_sizes, int n_in,
                              void* d_out, int out_size, void* d_ws, size_t ws_size,
                              hipStream_t stream)
{
  const float* x   = (const float*)d_in[0];
  const float* Wg  = (const float*)d_in[1];
  const float* bg  = (const float*)d_in[2];
  const float* W1  = (const float*)d_in[3];
  const float* b1  = (const float*)d_in[4];
  const float* g1  = (const float*)d_in[5];
  const float* be1 = (const float*)d_in[6];
  const float* W2  = (const float*)d_in[7];
  const float* b2  = (const float*)d_in[8];
  const float* g2  = (const float*)d_in[9];
  const float* be2 = (const float*)d_in[10];
  float* out = (float*)d_out;
  float* gate_out = out + (size_t)NT * H_DIM;

  char* ws = (char*)d_ws;
  size_t off = 0;
  auto alloc = [&](size_t bytes) { char* p = ws + off; off += (bytes + 255) & ~(size_t)255; return p; };
  unsigned short* w1bt = (unsigned short*)alloc((size_t)NE * H_DIM * H_DIM * 2);
  unsigned short* w2bt = (unsigned short*)alloc((size_t)NE * H_DIM * H_DIM * 2);
  unsigned short* buf1 = (unsigned short*)alloc((size_t)NP * H_DIM * 2);
  unsigned short* buf2 = (unsigned short*)alloc((size_t)NP * H_DIM * 2);
  int*   tk_e      = (int*)alloc((size_t)NP * 4);
  float* tk_w      = (float*)alloc((size_t)NP * 4);
  int*   pairTok   = (int*)alloc((size_t)NP * 4);
  int*   pairExp   = (int*)alloc((size_t)NP * 4);
  int*   slots     = (int*)alloc((size_t)NP * 4);
  int*   blockHist = (int*)alloc(64 * 8 * 4);
  int*   blockBase = (int*)alloc(64 * 8 * 4);
  int*   count     = (int*)alloc(8 * 4);
  int*   offs      = (int*)alloc(8 * 4);
  int*   wl        = (int*)alloc(MAX_WG * 4);
  int*   wlCount   = (int*)alloc(4);
  (void)in_sizes; (void)n_in; (void)out_size; (void)ws_size;

  // Xb (bf16 copy of X) aliases buf2: consumed by gemm1 before gemm2 writes buf2.
  unsigned short* Xb = buf2;

  transpose_convert_kernel<<<dim3(16, 16, 16), 256, 0, stream>>>(W1, W2, w1bt, w2bt);
  xgate_kernel<<<dim3(NT / 4), 256, 0, stream>>>(x, Wg, bg, Xb, gate_out, tk_e, tk_w);
  hist_kernel<<<dim3(64), 256, 0, stream>>>(tk_e, blockHist);
  scan_kernel<<<dim3(1), 64, 0, stream>>>(blockHist, blockBase, count, offs);
  worklist_kernel<<<dim3(1), 256, 0, stream>>>(count, wl, wlCount);
  place_kernel<<<dim3(64), 256, 0, stream>>>(tk_e, blockBase, pairTok, pairExp, slots);
  gemm4_kernel<true><<<dim3(MAX_WG), 512, 0, stream>>>(
      Xb, w1bt, b1, pairTok, count, offs, wl, wlCount, buf1);
  ln_relu_kernel<<<dim3(NP / 4), 256, 0, stream>>>(buf1, g1, be1, pairExp);
  gemm4_kernel<false><<<dim3(MAX_WG), 512, 0, stream>>>(
      buf1, w2bt, b2, pairTok, count, offs, wl, wlCount, buf2);
  combine_kernel<<<dim3(NT / 4), 256, 0, stream>>>(
      buf2, x, g2, be2, slots, tk_e, tk_w, out);
}